// Round 13
// baseline (91.288 us; speedup 1.0000x reference)
//
#include <hip/hip_runtime.h>
#include <hip/hip_bf16.h>

#define N_NODES 4096
#define IN_DIMC 512
#define NHEADS 4
#define DHEAD 64
#define OUT_COLS 256  // NHEADS*DHEAD
#define HPB (N_NODES * DHEAD * 2)  // 512 KB per head

typedef __attribute__((ext_vector_type(8))) short short8;
typedef __attribute__((ext_vector_type(4))) float f32x4;

__device__ __forceinline__ short bf16b(float x) {
    return __builtin_bit_cast(short, __float2bfloat16(x));
}
__device__ __forceinline__ void gload16(const void* g, void* l) {
    __builtin_amdgcn_global_load_lds((const __attribute__((address_space(1))) void*)g,
                                     (__attribute__((address_space(3))) void*)l,
                                     16, 0, 0);
}
__device__ __forceinline__ void gload4(const void* g, void* l) {
    __builtin_amdgcn_global_load_lds((const __attribute__((address_space(1))) void*)g,
                                     (__attribute__((address_space(3))) void*)l,
                                     4, 0, 0);
}

// ---- Kernel A: fused {fp32 h-GEMM + hP/exp epilogue (R9-verbatim)} and
//      {pack v3: ballot -> LDS -> coalesced u64 chunk-major stores}.
// grid 640: blocks [0,512) gemm (128 m-tiles x 4 heads); [512,640) pack (32 rows each).
__global__ __launch_bounds__(256) void k_prep2(
    const float* __restrict__ A, const float* __restrict__ W,
    const float* __restrict__ att, const int* __restrict__ adj,
    char* __restrict__ hP, float* __restrict__ E1, float* __restrict__ F1,
    float* __restrict__ E2, float* __restrict__ F2,
    unsigned long long* __restrict__ bitsT)
{
    const int t = (int)threadIdx.x;
    if (blockIdx.x >= 512) {
        // ---- pack v3: 32 rows/block; u64 word per 64-j chunk: bitsT[j/64][i] ----
        __shared__ unsigned ldsbits[32][130];   // [rowLocal][2*chunk(+pad)]
        const int pb = (int)blockIdx.x - 512;   // 0..127
        const int i0p = pb * 32;
        const int w = t >> 6, lane = t & 63;
        #pragma unroll 2
        for (int rr = 0; rr < 8; ++rr) {
            const int rl = (w << 3) | rr;       // local row 0..31
            const int* arow = adj + (size_t)(i0p + rl) * N_NODES;
            for (int cb = 0; cb < 16; ++cb) {   // 4 u64-chunks per iter
                const int c = cb * 4;
                const int a0 = arow[(c + 0) * 64 + lane];
                const int a1 = arow[(c + 1) * 64 + lane];
                const int a2 = arow[(c + 2) * 64 + lane];
                const int a3 = arow[(c + 3) * 64 + lane];
                const unsigned long long m0 = __ballot(a0 != 0);
                const unsigned long long m1 = __ballot(a1 != 0);
                const unsigned long long m2 = __ballot(a2 != 0);
                const unsigned long long m3 = __ballot(a3 != 0);
                if (lane == 0) {
                    *(unsigned long long*)&ldsbits[rl][(c + 0) * 2] = m0;
                    *(unsigned long long*)&ldsbits[rl][(c + 1) * 2] = m1;
                    *(unsigned long long*)&ldsbits[rl][(c + 2) * 2] = m2;
                    *(unsigned long long*)&ldsbits[rl][(c + 3) * 2] = m3;
                }
            }
        }
        __syncthreads();
        // coalesced store: wave w -> chunks w*16..w*16+15, 2 chunks per instr
        #pragma unroll
        for (int it = 0; it < 8; ++it) {
            const int c = (w << 4) + it * 2 + (lane >> 5);
            const int r = lane & 31;
            const unsigned long long v =
                *(const unsigned long long*)&ldsbits[r][c * 2];
            bitsT[(size_t)c * N_NODES + i0p + r] = v;
        }
        return;
    }
    // ---- gemm: tile 32(nodes) x 64(d) = one head slice (R9-verbatim) ----
    __shared__ float As[32][36];
    __shared__ float Bs[32][68];
    __shared__ float ht[64][33];
    const int m0 = ((int)blockIdx.x & 127) * 32;
    const int head = (int)blockIdx.x >> 7;
    const int n0 = head * 64;
    const int tm = t & 7, tn = t >> 3;
    float acc[4][2] = {};
    for (int k0 = 0; k0 < IN_DIMC; k0 += 32) {
        {
            const int r = t >> 3, kc = (t & 7) << 2;
            float4 v0 = *(const float4*)(A + (size_t)(m0 + r) * IN_DIMC + k0 + kc);
            As[kc + 0][r] = v0.x; As[kc + 1][r] = v0.y; As[kc + 2][r] = v0.z; As[kc + 3][r] = v0.w;
            const int rb = t >> 4, nc = (t & 15) << 2;
            float4 w0 = *(const float4*)(W + (size_t)(k0 + rb) * OUT_COLS + n0 + nc);
            float4 w1 = *(const float4*)(W + (size_t)(k0 + rb + 16) * OUT_COLS + n0 + nc);
            *(float4*)&Bs[rb][nc] = w0;
            *(float4*)&Bs[rb + 16][nc] = w1;
        }
        __syncthreads();
        #pragma unroll
        for (int kk = 0; kk < 32; ++kk) {
            const f32x4 a = *(const f32x4*)&As[kk][tm << 2];
            const float b0 = Bs[kk][tn * 2], b1 = Bs[kk][tn * 2 + 1];
            #pragma unroll
            for (int i = 0; i < 4; ++i) {
                acc[i][0] = fmaf(a[i], b0, acc[i][0]);
                acc[i][1] = fmaf(a[i], b1, acc[i][1]);
            }
        }
        __syncthreads();
    }
    #pragma unroll
    for (int i = 0; i < 4; ++i) {
        ht[tn * 2 + 0][(tm << 2) + i] = acc[i][0];
        ht[tn * 2 + 1][(tm << 2) + i] = acc[i][1];
    }
    __syncthreads();
    {   // packed hP: (d,j) -> 16B-slot ((g*4 + d/16)*64 + qq*16 + d%16), g=j/32
        const int d = t >> 2, qq = t & 3;
        short8 hv;
        #pragma unroll
        for (int k = 0; k < 8; ++k) hv[k] = bf16b(ht[d][qq * 8 + k]);
        const size_t off16 = ((size_t)(m0 >> 5) * 4 + (d >> 4)) * 64 + qq * 16 + (d & 15);
        *(short8*)(hP + (size_t)head * HPB + off16 * 16) = hv;
    }
    {   // s1/s2 -> exp tables
        const int r = t >> 3, part = t & 7;
        float p1 = 0.f, p2 = 0.f;
        #pragma unroll
        for (int dd = 0; dd < 8; ++dd) {
            const int d = part * 8 + dd;
            const float v = ht[d][r];
            p1 = fmaf(v, att[head * 128 + d], p1);
            p2 = fmaf(v, att[head * 128 + 64 + d], p2);
        }
        p1 += __shfl_xor(p1, 1); p1 += __shfl_xor(p1, 2); p1 += __shfl_xor(p1, 4);
        p2 += __shfl_xor(p2, 1); p2 += __shfl_xor(p2, 2); p2 += __shfl_xor(p2, 4);
        if (part == 0) {
            const int idx = head * N_NODES + m0 + r;
            E1[idx] = __expf(p1);
            F1[idx] = __expf(0.2f * p1);
            E2[idx] = __expf(p2);
            F2[idx] = __expf(0.2f * p2);
        }
    }
}

// ---- Kernel C (R8 structure, tail fixed): 32-i waves, 64-j steps, depth-1 ----
// grid (128, 2): i-tile 32, j-half per block. Block 512 = 8 waves =
// 4 heads x 2 jsegs (1024 j each = 16 steps of 64 j).
// Per wave: private 2 x 9216B LDS buf: [hP 8KB][E2 256][F2 256][bits 256].
__global__ __launch_bounds__(512, 2) void k_gat(
    const unsigned long long* __restrict__ bitsT, const char* __restrict__ hP,
    const float* __restrict__ E1, const float* __restrict__ F1,
    const float* __restrict__ E2, const float* __restrict__ F2,
    float* __restrict__ pA, float* __restrict__ pB, float* __restrict__ pDen)
{
    __shared__ __align__(16) char stage[8 * 18432];   // 144 KB
    const int i0 = (int)blockIdx.x * 32;
    const int by = (int)blockIdx.y;
    const int t = (int)threadIdx.x;
    const int w = t >> 6, lane = t & 63, il = lane & 15, q = lane >> 4;
    const int head = w & 3, jseg = w >> 2;
    const int jbase = by * 2048 + jseg * 1024;        // 16 steps of 64 j
    char* myst = stage + w * 18432;
    const char* hPh = hP + (size_t)head * HPB;
    const float* E2h = E2 + head * N_NODES;
    const float* F2h = F2 + head * N_NODES;
    const float e1a = E1[head * N_NODES + i0 + il];
    const float e1b = E1[head * N_NODES + i0 + 16 + il];
    const float f1a = F1[head * N_NODES + i0 + il];
    const float f1b = F1[head * N_NODES + i0 + 16 + il];
    f32x4 acc[4][2] = {};
    f32x4 accD[2] = {};
    short8 ones;
    #pragma unroll
    for (int e = 0; e < 8; ++e) ones[e] = (short)0x3F80;

    const int g0 = jbase >> 5;      // 32-j tile index base (2 tiles per step)
    const int c0 = jbase >> 6;      // 64-j chunk base
    // one batch = 11 gloads: 8 hP + E2 + F2 + bits
    auto issue = [&](int bs, char* dst) {
        const char* hsrc = hPh + (size_t)(g0 + bs * 2) * 4096;
        #pragma unroll
        for (int k = 0; k < 8; ++k)
            gload16(hsrc + k * 1024 + lane * 16, dst + k * 1024);
        gload4(E2h + jbase + bs * 64 + lane, dst + 8192);
        gload4(F2h + jbase + bs * 64 + lane, dst + 8448);
        gload4((const char*)(bitsT + (size_t)(c0 + bs) * N_NODES + i0) + lane * 4,
               dst + 8704);
    };
    issue(0, myst);
    #pragma unroll 2
    for (int s = 0; s < 16; ++s) {
        if (s < 15) {
            issue(s + 1, myst + ((s + 1) & 1) * 9216);
            asm volatile("s_waitcnt vmcnt(11)" ::: "memory");  // batch s landed
        } else {
            asm volatile("s_waitcnt vmcnt(0)" ::: "memory");   // drain: no epilogue race
        }
        const char* base = myst + (s & 1) * 9216;
        const unsigned long long bitsA = *(const unsigned long long*)(base + 8704 + il * 8);
        const unsigned long long bitsB = *(const unsigned long long*)(base + 8704 + 128 + il * 8);
        #pragma unroll
        for (int h = 0; h < 2; ++h) {
            const f32x4 ea = *(const f32x4*)(base + 8192 + h * 128 + q * 32);
            const f32x4 eb = *(const f32x4*)(base + 8192 + h * 128 + q * 32 + 16);
            const f32x4 fa = *(const f32x4*)(base + 8448 + h * 128 + q * 32);
            const f32x4 fb2 = *(const f32x4*)(base + 8448 + h * 128 + q * 32 + 16);
            const unsigned mA = (unsigned)(bitsA >> (h * 32 + q * 8)) & 0xffu;
            const unsigned mB = (unsigned)(bitsB >> (h * 32 + q * 8)) & 0xffu;
            short8 afA, afB;
            #pragma unroll
            for (int e = 0; e < 8; ++e) {
                const float Ev = (e < 4) ? ea[e] : eb[e - 4];
                const float Fv = (e < 4) ? fa[e] : fb2[e - 4];
                const float pa = fmaxf(e1a * Ev, f1a * Fv);
                const float pb = fmaxf(e1b * Ev, f1b * Fv);
                afA[e] = bf16b(((mA >> e) & 1u) ? pa : 0.f);
                afB[e] = bf16b(((mB >> e) & 1u) ? pb : 0.f);
            }
            #pragma unroll
            for (int dblk = 0; dblk < 4; ++dblk) {
                const short8 bfrag = *(const short8*)(base + h * 4096 + dblk * 1024 + lane * 16);
                acc[dblk][0] = __builtin_amdgcn_mfma_f32_16x16x32_bf16(afA, bfrag, acc[dblk][0], 0, 0, 0);
                acc[dblk][1] = __builtin_amdgcn_mfma_f32_16x16x32_bf16(afB, bfrag, acc[dblk][1], 0, 0, 0);
            }
            accD[0] = __builtin_amdgcn_mfma_f32_16x16x32_bf16(afA, ones, accD[0], 0, 0, 0);
            accD[1] = __builtin_amdgcn_mfma_f32_16x16x32_bf16(afB, ones, accD[1], 0, 0, 0);
        }
    }
    // ---- epilogue: jseg-pair reduction in LDS, write partials for half 'by' ----
    __syncthreads();
    float* ep = (float*)stage;           // 4 waves x 2560 f32 = 40 KB
    if (jseg == 1) {
        float* dst = ep + (w - 4) * 2560;
        #pragma unroll
        for (int dblk = 0; dblk < 4; ++dblk)
            #pragma unroll
            for (int sub = 0; sub < 2; ++sub)
                #pragma unroll
                for (int r = 0; r < 4; ++r)
                    dst[(dblk * 8 + sub * 4 + r) * 64 + lane] = acc[dblk][sub][r];
        #pragma unroll
        for (int sub = 0; sub < 2; ++sub)
            #pragma unroll
            for (int r = 0; r < 4; ++r)
                dst[(32 + sub * 4 + r) * 64 + lane] = accD[sub][r];
    }
    __syncthreads();
    if (jseg == 0) {
        const float* src = ep + w * 2560;
        float* po = (by == 0) ? pA : pB;
        #pragma unroll
        for (int sub = 0; sub < 2; ++sub) {
            #pragma unroll
            for (int r = 0; r < 4; ++r) {
                const int row = i0 + sub * 16 + q * 4 + r;   // C/D: row=(lane>>4)*4+reg
                #pragma unroll
                for (int dblk = 0; dblk < 4; ++dblk) {
                    const float v = acc[dblk][sub][r] + src[(dblk * 8 + sub * 4 + r) * 64 + lane];
                    po[(size_t)row * OUT_COLS + head * DHEAD + dblk * 16 + il] = v;
                }
                if (il == 0) {
                    const float d = accD[sub][r] + src[(32 + sub * 4 + r) * 64 + lane];
                    pDen[by * (NHEADS * N_NODES) + head * N_NODES + row] = d;
                }
            }
        }
    }
}

// ---- Kernel F: combine 2 j-half partials, divide, bias ----
__global__ __launch_bounds__(256) void k_fin(
    const float* __restrict__ pB, const float* __restrict__ pDen,
    const float* __restrict__ bias, float* __restrict__ outp)
{
    const int gid = (int)blockIdx.x * 256 + (int)threadIdx.x;  // 262144
    const int i = gid >> 6;
    const int c4 = (gid & 63) << 2;
    const int head = c4 >> 6;
    const float4 v0 = *(const float4*)(outp + (size_t)i * OUT_COLS + c4);
    const float4 v1 = *(const float4*)(pB + (size_t)i * OUT_COLS + c4);
    const float d = pDen[head * N_NODES + i] + pDen[NHEADS * N_NODES + head * N_NODES + i];
    const float inv = 1.0f / d;
    const float4 bb = *(const float4*)(bias + c4);
    float4 r;
    r.x = (v0.x + v1.x) * inv + bb.x;
    r.y = (v0.y + v1.y) * inv + bb.y;
    r.z = (v0.z + v1.z) * inv + bb.z;
    r.w = (v0.w + v1.w) * inv + bb.w;
    *(float4*)(outp + (size_t)i * OUT_COLS + c4) = r;
}

extern "C" void kernel_launch(void* const* d_in, const int* in_sizes, int n_in,
                              void* d_out, int out_size, void* d_ws, size_t ws_size,
                              hipStream_t stream) {
    const float* features  = (const float*)d_in[0];
    const int*   adjacency = (const int*)d_in[1];
    const float* weights   = (const float*)d_in[2];
    const float* attention = (const float*)d_in[3];
    const float* bias      = (const float*)d_in[4];
    float* out = (float*)d_out;

    char* ws = (char*)d_ws;
    char*  hP = ws;                                              // 2 MB
    float* E1 = (float*)(ws + 2u*1024*1024);                     // 64 KB
    float* F1 = (float*)(ws + 2u*1024*1024 +  64u*1024);
    float* E2 = (float*)(ws + 2u*1024*1024 + 128u*1024);
    float* F2 = (float*)(ws + 2u*1024*1024 + 192u*1024);
    unsigned long long* bitsT =
        (unsigned long long*)(ws + 2u*1024*1024 + 256u*1024);    // 2 MB
    float* pB   = (float*)(ws + 4u*1024*1024 + 256u*1024);       // 4 MB
    float* pDen = (float*)(ws + 8u*1024*1024 + 256u*1024);       // 128 KB

    k_prep2<<<dim3(640), 256, 0, stream>>>(features, weights, attention, adjacency,
                                           hP, E1, F1, E2, F2, bitsT);
    k_gat<<<dim3(128, 2), 512, 0, stream>>>(bitsT, hP, E1, F1, E2, F2,
                                            out /*pA*/, pB, pDen);
    k_fin<<<dim3(1024), 256, 0, stream>>>(pB, pDen, bias, out);
}

// Round 14
// 69.305 us; speedup vs baseline: 1.3172x; 1.3172x over previous
//
#include <hip/hip_runtime.h>
#include <hip/hip_bf16.h>

#define N_NODES 4096
#define IN_DIMC 512
#define NHEADS 4
#define DHEAD 64
#define OUT_COLS 256  // NHEADS*DHEAD
#define HPB (N_NODES * DHEAD * 2)  // 512 KB per head

typedef __attribute__((ext_vector_type(8))) short short8;
typedef __attribute__((ext_vector_type(4))) float f32x4;

__device__ __forceinline__ short bf16b(float x) {
    return __builtin_bit_cast(short, __float2bfloat16(x));
}
__device__ __forceinline__ void gload16(const void* g, void* l) {
    __builtin_amdgcn_global_load_lds((const __attribute__((address_space(1))) void*)g,
                                     (__attribute__((address_space(3))) void*)l,
                                     16, 0, 0);
}
__device__ __forceinline__ void gload4(const void* g, void* l) {
    __builtin_amdgcn_global_load_lds((const __attribute__((address_space(1))) void*)g,
                                     (__attribute__((address_space(3))) void*)l,
                                     4, 0, 0);
}

// ---- Kernel P (v4): adjacency -> u64 bitmask bitsT[j/64][i] ----
// 512 blocks x 4 waves x 2 rows/wave = 4096 parallel row-chains.
// Per iter: 2 rows x 4 chunks = 8 loads in flight; 16 iters total.
// Store: ulonglong2 = chunk-word for rows (r0, r0+1) -> 16B coalesced-ish.
__global__ __launch_bounds__(256) void k_pack(
    const int* __restrict__ adj, unsigned long long* __restrict__ bitsT)
{
    const int t = (int)threadIdx.x;
    const int wv = t >> 6, lane = t & 63;
    const int r0 = (int)blockIdx.x * 8 + wv * 2;   // rows r0, r0+1
    const int* arow0 = adj + (size_t)r0 * N_NODES;
    const int* arow1 = arow0 + N_NODES;
    for (int cb = 0; cb < 16; ++cb) {
        const int c = cb * 4;
        int a0[4], a1[4];
        #pragma unroll
        for (int k = 0; k < 4; ++k) {
            a0[k] = arow0[(c + k) * 64 + lane];
            a1[k] = arow1[(c + k) * 64 + lane];
        }
        unsigned long long m0[4], m1[4];
        #pragma unroll
        for (int k = 0; k < 4; ++k) {
            m0[k] = __ballot(a0[k] != 0);
            m1[k] = __ballot(a1[k] != 0);
        }
        if (lane == 0) {
            #pragma unroll
            for (int k = 0; k < 4; ++k) {
                ulonglong2 v;
                v.x = m0[k]; v.y = m1[k];
                *(ulonglong2*)&bitsT[(size_t)(c + k) * N_NODES + r0] = v;
            }
        }
    }
}

// ---- Kernel G: fp32 h-GEMM + hP/exp-table epilogue (R9-verbatim, standalone) ----
// grid 512: 128 m-tiles x 4 heads, tile 32(nodes) x 64(d).
__global__ __launch_bounds__(256) void k_gemm(
    const float* __restrict__ A, const float* __restrict__ W,
    const float* __restrict__ att,
    char* __restrict__ hP, float* __restrict__ E1, float* __restrict__ F1,
    float* __restrict__ E2, float* __restrict__ F2)
{
    __shared__ float As[32][36];
    __shared__ float Bs[32][68];
    __shared__ float ht[64][33];
    const int t = (int)threadIdx.x;
    const int m0 = ((int)blockIdx.x & 127) * 32;
    const int head = (int)blockIdx.x >> 7;
    const int n0 = head * 64;
    const int tm = t & 7, tn = t >> 3;
    float acc[4][2] = {};
    for (int k0 = 0; k0 < IN_DIMC; k0 += 32) {
        {
            const int r = t >> 3, kc = (t & 7) << 2;
            float4 v0 = *(const float4*)(A + (size_t)(m0 + r) * IN_DIMC + k0 + kc);
            As[kc + 0][r] = v0.x; As[kc + 1][r] = v0.y; As[kc + 2][r] = v0.z; As[kc + 3][r] = v0.w;
            const int rb = t >> 4, nc = (t & 15) << 2;
            float4 w0 = *(const float4*)(W + (size_t)(k0 + rb) * OUT_COLS + n0 + nc);
            float4 w1 = *(const float4*)(W + (size_t)(k0 + rb + 16) * OUT_COLS + n0 + nc);
            *(float4*)&Bs[rb][nc] = w0;
            *(float4*)&Bs[rb + 16][nc] = w1;
        }
        __syncthreads();
        #pragma unroll
        for (int kk = 0; kk < 32; ++kk) {
            const f32x4 a = *(const f32x4*)&As[kk][tm << 2];
            const float b0 = Bs[kk][tn * 2], b1 = Bs[kk][tn * 2 + 1];
            #pragma unroll
            for (int i = 0; i < 4; ++i) {
                acc[i][0] = fmaf(a[i], b0, acc[i][0]);
                acc[i][1] = fmaf(a[i], b1, acc[i][1]);
            }
        }
        __syncthreads();
    }
    #pragma unroll
    for (int i = 0; i < 4; ++i) {
        ht[tn * 2 + 0][(tm << 2) + i] = acc[i][0];
        ht[tn * 2 + 1][(tm << 2) + i] = acc[i][1];
    }
    __syncthreads();
    {   // packed hP: (d,j) -> 16B-slot ((g*4 + d/16)*64 + qq*16 + d%16), g=j/32
        const int d = t >> 2, qq = t & 3;
        short8 hv;
        #pragma unroll
        for (int k = 0; k < 8; ++k) hv[k] = bf16b(ht[d][qq * 8 + k]);
        const size_t off16 = ((size_t)(m0 >> 5) * 4 + (d >> 4)) * 64 + qq * 16 + (d & 15);
        *(short8*)(hP + (size_t)head * HPB + off16 * 16) = hv;
    }
    {   // s1/s2 -> exp tables
        const int r = t >> 3, part = t & 7;
        float p1 = 0.f, p2 = 0.f;
        #pragma unroll
        for (int dd = 0; dd < 8; ++dd) {
            const int d = part * 8 + dd;
            const float v = ht[d][r];
            p1 = fmaf(v, att[head * 128 + d], p1);
            p2 = fmaf(v, att[head * 128 + 64 + d], p2);
        }
        p1 += __shfl_xor(p1, 1); p1 += __shfl_xor(p1, 2); p1 += __shfl_xor(p1, 4);
        p2 += __shfl_xor(p2, 1); p2 += __shfl_xor(p2, 2); p2 += __shfl_xor(p2, 4);
        if (part == 0) {
            const int idx = head * N_NODES + m0 + r;
            E1[idx] = __expf(p1);
            F1[idx] = __expf(0.2f * p1);
            E2[idx] = __expf(p2);
            F2[idx] = __expf(0.2f * p2);
        }
    }
}

// ---- Kernel C (R13-verbatim): 32-i waves, 64-j steps, depth-1, tail fixed ----
// grid (128, 2): i-tile 32, j-half per block. Block 512 = 8 waves =
// 4 heads x 2 jsegs (1024 j each = 16 steps of 64 j).
// Per wave: private 2 x 9216B LDS buf: [hP 8KB][E2 256][F2 256][bits 256].
__global__ __launch_bounds__(512, 2) void k_gat(
    const unsigned long long* __restrict__ bitsT, const char* __restrict__ hP,
    const float* __restrict__ E1, const float* __restrict__ F1,
    const float* __restrict__ E2, const float* __restrict__ F2,
    float* __restrict__ pA, float* __restrict__ pB, float* __restrict__ pDen)
{
    __shared__ __align__(16) char stage[8 * 18432];   // 144 KB
    const int i0 = (int)blockIdx.x * 32;
    const int by = (int)blockIdx.y;
    const int t = (int)threadIdx.x;
    const int w = t >> 6, lane = t & 63, il = lane & 15, q = lane >> 4;
    const int head = w & 3, jseg = w >> 2;
    const int jbase = by * 2048 + jseg * 1024;        // 16 steps of 64 j
    char* myst = stage + w * 18432;
    const char* hPh = hP + (size_t)head * HPB;
    const float* E2h = E2 + head * N_NODES;
    const float* F2h = F2 + head * N_NODES;
    const float e1a = E1[head * N_NODES + i0 + il];
    const float e1b = E1[head * N_NODES + i0 + 16 + il];
    const float f1a = F1[head * N_NODES + i0 + il];
    const float f1b = F1[head * N_NODES + i0 + 16 + il];
    f32x4 acc[4][2] = {};
    f32x4 accD[2] = {};
    short8 ones;
    #pragma unroll
    for (int e = 0; e < 8; ++e) ones[e] = (short)0x3F80;

    const int g0 = jbase >> 5;      // 32-j tile index base (2 tiles per step)
    const int c0 = jbase >> 6;      // 64-j chunk base
    // one batch = 11 gloads: 8 hP + E2 + F2 + bits
    auto issue = [&](int bs, char* dst) {
        const char* hsrc = hPh + (size_t)(g0 + bs * 2) * 4096;
        #pragma unroll
        for (int k = 0; k < 8; ++k)
            gload16(hsrc + k * 1024 + lane * 16, dst + k * 1024);
        gload4(E2h + jbase + bs * 64 + lane, dst + 8192);
        gload4(F2h + jbase + bs * 64 + lane, dst + 8448);
        gload4((const char*)(bitsT + (size_t)(c0 + bs) * N_NODES + i0) + lane * 4,
               dst + 8704);
    };
    issue(0, myst);
    #pragma unroll 2
    for (int s = 0; s < 16; ++s) {
        if (s < 15) {
            issue(s + 1, myst + ((s + 1) & 1) * 9216);
            asm volatile("s_waitcnt vmcnt(11)" ::: "memory");  // batch s landed
        } else {
            asm volatile("s_waitcnt vmcnt(0)" ::: "memory");   // drain: no epilogue race
        }
        const char* base = myst + (s & 1) * 9216;
        const unsigned long long bitsA = *(const unsigned long long*)(base + 8704 + il * 8);
        const unsigned long long bitsB = *(const unsigned long long*)(base + 8704 + 128 + il * 8);
        #pragma unroll
        for (int h = 0; h < 2; ++h) {
            const f32x4 ea = *(const f32x4*)(base + 8192 + h * 128 + q * 32);
            const f32x4 eb = *(const f32x4*)(base + 8192 + h * 128 + q * 32 + 16);
            const f32x4 fa = *(const f32x4*)(base + 8448 + h * 128 + q * 32);
            const f32x4 fb2 = *(const f32x4*)(base + 8448 + h * 128 + q * 32 + 16);
            const unsigned mA = (unsigned)(bitsA >> (h * 32 + q * 8)) & 0xffu;
            const unsigned mB = (unsigned)(bitsB >> (h * 32 + q * 8)) & 0xffu;
            short8 afA, afB;
            #pragma unroll
            for (int e = 0; e < 8; ++e) {
                const float Ev = (e < 4) ? ea[e] : eb[e - 4];
                const float Fv = (e < 4) ? fa[e] : fb2[e - 4];
                const float pa = fmaxf(e1a * Ev, f1a * Fv);
                const float pb = fmaxf(e1b * Ev, f1b * Fv);
                afA[e] = bf16b(((mA >> e) & 1u) ? pa : 0.f);
                afB[e] = bf16b(((mB >> e) & 1u) ? pb : 0.f);
            }
            #pragma unroll
            for (int dblk = 0; dblk < 4; ++dblk) {
                const short8 bfrag = *(const short8*)(base + h * 4096 + dblk * 1024 + lane * 16);
                acc[dblk][0] = __builtin_amdgcn_mfma_f32_16x16x32_bf16(afA, bfrag, acc[dblk][0], 0, 0, 0);
                acc[dblk][1] = __builtin_amdgcn_mfma_f32_16x16x32_bf16(afB, bfrag, acc[dblk][1], 0, 0, 0);
            }
            accD[0] = __builtin_amdgcn_mfma_f32_16x16x32_bf16(afA, ones, accD[0], 0, 0, 0);
            accD[1] = __builtin_amdgcn_mfma_f32_16x16x32_bf16(afB, ones, accD[1], 0, 0, 0);
        }
    }
    // ---- epilogue: jseg-pair reduction in LDS, write partials for half 'by' ----
    __syncthreads();
    float* ep = (float*)stage;           // 4 waves x 2560 f32 = 40 KB
    if (jseg == 1) {
        float* dst = ep + (w - 4) * 2560;
        #pragma unroll
        for (int dblk = 0; dblk < 4; ++dblk)
            #pragma unroll
            for (int sub = 0; sub < 2; ++sub)
                #pragma unroll
                for (int r = 0; r < 4; ++r)
                    dst[(dblk * 8 + sub * 4 + r) * 64 + lane] = acc[dblk][sub][r];
        #pragma unroll
        for (int sub = 0; sub < 2; ++sub)
            #pragma unroll
            for (int r = 0; r < 4; ++r)
                dst[(32 + sub * 4 + r) * 64 + lane] = accD[sub][r];
    }
    __syncthreads();
    if (jseg == 0) {
        const float* src = ep + w * 2560;
        float* po = (by == 0) ? pA : pB;
        #pragma unroll
        for (int sub = 0; sub < 2; ++sub) {
            #pragma unroll
            for (int r = 0; r < 4; ++r) {
                const int row = i0 + sub * 16 + q * 4 + r;   // C/D: row=(lane>>4)*4+reg
                #pragma unroll
                for (int dblk = 0; dblk < 4; ++dblk) {
                    const float v = acc[dblk][sub][r] + src[(dblk * 8 + sub * 4 + r) * 64 + lane];
                    po[(size_t)row * OUT_COLS + head * DHEAD + dblk * 16 + il] = v;
                }
                if (il == 0) {
                    const float d = accD[sub][r] + src[(32 + sub * 4 + r) * 64 + lane];
                    pDen[by * (NHEADS * N_NODES) + head * N_NODES + row] = d;
                }
            }
        }
    }
}

// ---- Kernel F: combine 2 j-half partials, divide, bias ----
__global__ __launch_bounds__(256) void k_fin(
    const float* __restrict__ pB, const float* __restrict__ pDen,
    const float* __restrict__ bias, float* __restrict__ outp)
{
    const int gid = (int)blockIdx.x * 256 + (int)threadIdx.x;  // 262144
    const int i = gid >> 6;
    const int c4 = (gid & 63) << 2;
    const int head = c4 >> 6;
    const float4 v0 = *(const float4*)(outp + (size_t)i * OUT_COLS + c4);
    const float4 v1 = *(const float4*)(pB + (size_t)i * OUT_COLS + c4);
    const float d = pDen[head * N_NODES + i] + pDen[NHEADS * N_NODES + head * N_NODES + i];
    const float inv = 1.0f / d;
    const float4 bb = *(const float4*)(bias + c4);
    float4 r;
    r.x = (v0.x + v1.x) * inv + bb.x;
    r.y = (v0.y + v1.y) * inv + bb.y;
    r.z = (v0.z + v1.z) * inv + bb.z;
    r.w = (v0.w + v1.w) * inv + bb.w;
    *(float4*)(outp + (size_t)i * OUT_COLS + c4) = r;
}

extern "C" void kernel_launch(void* const* d_in, const int* in_sizes, int n_in,
                              void* d_out, int out_size, void* d_ws, size_t ws_size,
                              hipStream_t stream) {
    const float* features  = (const float*)d_in[0];
    const int*   adjacency = (const int*)d_in[1];
    const float* weights   = (const float*)d_in[2];
    const float* attention = (const float*)d_in[3];
    const float* bias      = (const float*)d_in[4];
    float* out = (float*)d_out;

    char* ws = (char*)d_ws;
    char*  hP = ws;                                              // 2 MB
    float* E1 = (float*)(ws + 2u*1024*1024);                     // 64 KB
    float* F1 = (float*)(ws + 2u*1024*1024 +  64u*1024);
    float* E2 = (float*)(ws + 2u*1024*1024 + 128u*1024);
    float* F2 = (float*)(ws + 2u*1024*1024 + 192u*1024);
    unsigned long long* bitsT =
        (unsigned long long*)(ws + 2u*1024*1024 + 256u*1024);    // 2 MB
    float* pB   = (float*)(ws + 4u*1024*1024 + 256u*1024);       // 4 MB
    float* pDen = (float*)(ws + 8u*1024*1024 + 256u*1024);       // 128 KB

    k_pack<<<dim3(512), 256, 0, stream>>>(adjacency, bitsT);
    k_gemm<<<dim3(512), 256, 0, stream>>>(features, weights, attention,
                                          hP, E1, F1, E2, F2);
    k_gat<<<dim3(128, 2), 512, 0, stream>>>(bitsT, hP, E1, F1, E2, F2,
                                            out /*pA*/, pB, pDen);
    k_fin<<<dim3(1024), 256, 0, stream>>>(pB, pDen, bias, out);
}

// Round 15
// 60.200 us; speedup vs baseline: 1.5164x; 1.1513x over previous
//
#include <hip/hip_runtime.h>
#include <hip/hip_bf16.h>

#define N_NODES 4096
#define IN_DIMC 512
#define NHEADS 4
#define DHEAD 64
#define OUT_COLS 256  // NHEADS*DHEAD
#define HPB (N_NODES * DHEAD * 2)  // 512 KB per head

typedef __attribute__((ext_vector_type(8))) short short8;
typedef __attribute__((ext_vector_type(4))) float f32x4;

// Tile-local j permutation (R15): within each 32-j tile, (q, e) <-> j = 4e + q.
// Applied consistently to: bits32 words (pack), hP fragment order, E2p/F2p tables.
// k_gat's inner loop is UNCHANGED; PV/denoms are j-order invariant.

__device__ __forceinline__ short bf16b(float x) {
    return __builtin_bit_cast(short, __float2bfloat16(x));
}
__device__ __forceinline__ void gload16(const void* g, void* l) {
    __builtin_amdgcn_global_load_lds((const __attribute__((address_space(1))) void*)g,
                                     (__attribute__((address_space(3))) void*)l,
                                     16, 0, 0);
}
__device__ __forceinline__ void gload4(const void* g, void* l) {
    __builtin_amdgcn_global_load_lds((const __attribute__((address_space(1))) void*)g,
                                     (__attribute__((address_space(3))) void*)l,
                                     4, 0, 0);
}

// ---- Kernel A: fused {fp32 h-GEMM + permuted hP/exp epilogue} + {int4-ballot pack} ----
// grid 1536: blocks [0,512) gemm (128 m-tiles x 4 heads); [512,1536) pack (4 rows/block).
__global__ __launch_bounds__(256) void k_prep2(
    const float* __restrict__ A, const float* __restrict__ W,
    const float* __restrict__ att, const int* __restrict__ adj,
    char* __restrict__ hP, float* __restrict__ E1, float* __restrict__ F1,
    float* __restrict__ E2p, float* __restrict__ F2p,
    unsigned* __restrict__ bits32)
{
    const int t = (int)threadIdx.x;
    if (blockIdx.x >= 512) {
        // ---- pack: 1 row/wave, int4 loads (16B/lane), 4 ballots -> 8 tile-words ----
        // word for tile g = 8*it + s: bit (8k+m) <-> j = 32*g + 4m + k.
        const int pb = (int)blockIdx.x - 512;       // 0..1023
        const int i = pb * 4 + (t >> 6);            // row 0..4095
        const int lane = t & 63;
        const int4* arow = (const int4*)(adj + (size_t)i * N_NODES);
        #pragma unroll 2
        for (int it = 0; it < 16; ++it) {
            const int4 a = arow[it * 64 + lane];    // ints 256*it + 4*lane .. +3
            const unsigned long long m0 = __ballot(a.x != 0);
            const unsigned long long m1 = __ballot(a.y != 0);
            const unsigned long long m2 = __ballot(a.z != 0);
            const unsigned long long m3 = __ballot(a.w != 0);
            if (lane < 8) {
                const int sh = lane * 8;
                const unsigned wv =
                      ((unsigned)(m0 >> sh) & 0xffu)
                    | (((unsigned)(m1 >> sh) & 0xffu) << 8)
                    | (((unsigned)(m2 >> sh) & 0xffu) << 16)
                    | (((unsigned)(m3 >> sh) & 0xffu) << 24);
                bits32[(size_t)(it * 8 + lane) * N_NODES + i] = wv;
            }
        }
        return;
    }
    // ---- gemm: tile 32(nodes) x 64(d) = one head slice (R9-verbatim core) ----
    __shared__ float As[32][36];
    __shared__ float Bs[32][68];
    __shared__ float ht[64][33];
    const int m0 = ((int)blockIdx.x & 127) * 32;
    const int head = (int)blockIdx.x >> 7;
    const int n0 = head * 64;
    const int tm = t & 7, tn = t >> 3;
    float acc[4][2] = {};
    for (int k0 = 0; k0 < IN_DIMC; k0 += 32) {
        {
            const int r = t >> 3, kc = (t & 7) << 2;
            float4 v0 = *(const float4*)(A + (size_t)(m0 + r) * IN_DIMC + k0 + kc);
            As[kc + 0][r] = v0.x; As[kc + 1][r] = v0.y; As[kc + 2][r] = v0.z; As[kc + 3][r] = v0.w;
            const int rb = t >> 4, nc = (t & 15) << 2;
            float4 w0 = *(const float4*)(W + (size_t)(k0 + rb) * OUT_COLS + n0 + nc);
            float4 w1 = *(const float4*)(W + (size_t)(k0 + rb + 16) * OUT_COLS + n0 + nc);
            *(float4*)&Bs[rb][nc] = w0;
            *(float4*)&Bs[rb + 16][nc] = w1;
        }
        __syncthreads();
        #pragma unroll
        for (int kk = 0; kk < 32; ++kk) {
            const f32x4 a = *(const f32x4*)&As[kk][tm << 2];
            const float b0 = Bs[kk][tn * 2], b1 = Bs[kk][tn * 2 + 1];
            #pragma unroll
            for (int i = 0; i < 4; ++i) {
                acc[i][0] = fmaf(a[i], b0, acc[i][0]);
                acc[i][1] = fmaf(a[i], b1, acc[i][1]);
            }
        }
        __syncthreads();
    }
    #pragma unroll
    for (int i = 0; i < 4; ++i) {
        ht[tn * 2 + 0][(tm << 2) + i] = acc[i][0];
        ht[tn * 2 + 1][(tm << 2) + i] = acc[i][1];
    }
    __syncthreads();
    {   // permuted hP: slot(g,dblk,qq,il) element e = h[d][32g + 4e + qq]
        const int d = t >> 2, qq = t & 3;
        short8 hv;
        #pragma unroll
        for (int e = 0; e < 8; ++e) hv[e] = bf16b(ht[d][4 * e + qq]);
        const size_t off16 = ((size_t)(m0 >> 5) * 4 + (d >> 4)) * 64 + qq * 16 + (d & 15);
        *(short8*)(hP + (size_t)head * HPB + off16 * 16) = hv;
    }
    {   // s1/s2 -> E1/F1 (natural order), E2p/F2p (tile-permuted order)
        const int r = t >> 3, part = t & 7;
        float p1 = 0.f, p2 = 0.f;
        #pragma unroll
        for (int dd = 0; dd < 8; ++dd) {
            const int d = part * 8 + dd;
            const float v = ht[d][r];
            p1 = fmaf(v, att[head * 128 + d], p1);
            p2 = fmaf(v, att[head * 128 + 64 + d], p2);
        }
        p1 += __shfl_xor(p1, 1); p1 += __shfl_xor(p1, 2); p1 += __shfl_xor(p1, 4);
        p2 += __shfl_xor(p2, 1); p2 += __shfl_xor(p2, 2); p2 += __shfl_xor(p2, 4);
        if (part == 0) {
            const int idx = head * N_NODES + m0 + r;
            const int idxp = head * N_NODES + m0 + ((r & 3) << 3) + (r >> 2);
            E1[idx] = __expf(p1);
            F1[idx] = __expf(0.2f * p1);
            E2p[idxp] = __expf(p2);
            F2p[idxp] = __expf(0.2f * p2);
        }
    }
}

// ---- Kernel C (R14 structure; bits32 u32-tile-words): 32-i, 64-j steps, depth-1 ----
// grid (128, 2): i-tile 32, j-half per block. Block 512 = 8 waves =
// 4 heads x 2 jsegs (1024 j each = 16 steps of 64 j).
// Per wave: private 2 x 9216B LDS buf: [hP 8KB][E2p 256][F2p 256][bits 256].
__global__ __launch_bounds__(512, 2) void k_gat(
    const unsigned* __restrict__ bits32, const char* __restrict__ hP,
    const float* __restrict__ E1, const float* __restrict__ F1,
    const float* __restrict__ E2p, const float* __restrict__ F2p,
    float* __restrict__ pA, float* __restrict__ pB, float* __restrict__ pDen)
{
    __shared__ __align__(16) char stage[8 * 18432];   // 144 KB
    const int i0 = (int)blockIdx.x * 32;
    const int by = (int)blockIdx.y;
    const int t = (int)threadIdx.x;
    const int w = t >> 6, lane = t & 63, il = lane & 15, q = lane >> 4;
    const int head = w & 3, jseg = w >> 2;
    const int jbase = by * 2048 + jseg * 1024;        // 16 steps of 64 j
    char* myst = stage + w * 18432;
    const char* hPh = hP + (size_t)head * HPB;
    const float* E2h = E2p + head * N_NODES;
    const float* F2h = F2p + head * N_NODES;
    const float e1a = E1[head * N_NODES + i0 + il];
    const float e1b = E1[head * N_NODES + i0 + 16 + il];
    const float f1a = F1[head * N_NODES + i0 + il];
    const float f1b = F1[head * N_NODES + i0 + 16 + il];
    f32x4 acc[4][2] = {};
    f32x4 accD[2] = {};
    short8 ones;
    #pragma unroll
    for (int e = 0; e < 8; ++e) ones[e] = (short)0x3F80;

    const int g0 = jbase >> 5;      // 32-j tile index base (2 tiles per step)
    // one batch = 11 gloads: 8 hP + E2p + F2p + bits (2 tiles x 32 rows of u32)
    auto issue = [&](int bs, char* dst) {
        const char* hsrc = hPh + (size_t)(g0 + bs * 2) * 4096;
        #pragma unroll
        for (int k = 0; k < 8; ++k)
            gload16(hsrc + k * 1024 + lane * 16, dst + k * 1024);
        gload4(E2h + jbase + bs * 64 + lane, dst + 8192);
        gload4(F2h + jbase + bs * 64 + lane, dst + 8448);
        gload4((const char*)bits32 +
               ((size_t)(g0 + bs * 2 + (lane >> 5)) * N_NODES + i0 + (lane & 31)) * 4,
               dst + 8704);
    };
    issue(0, myst);
    #pragma unroll 2
    for (int s = 0; s < 16; ++s) {
        if (s < 15) {
            issue(s + 1, myst + ((s + 1) & 1) * 9216);
            asm volatile("s_waitcnt vmcnt(11)" ::: "memory");  // batch s landed
        } else {
            asm volatile("s_waitcnt vmcnt(0)" ::: "memory");   // drain: no epilogue race
        }
        const char* base = myst + (s & 1) * 9216;
        #pragma unroll
        for (int h = 0; h < 2; ++h) {
            const f32x4 ea = *(const f32x4*)(base + 8192 + h * 128 + q * 32);
            const f32x4 eb = *(const f32x4*)(base + 8192 + h * 128 + q * 32 + 16);
            const f32x4 fa = *(const f32x4*)(base + 8448 + h * 128 + q * 32);
            const f32x4 fb2 = *(const f32x4*)(base + 8448 + h * 128 + q * 32 + 16);
            const unsigned uA = *(const unsigned*)(base + 8704 + h * 128 + il * 4);
            const unsigned uB = *(const unsigned*)(base + 8704 + h * 128 + 64 + il * 4);
            const unsigned mA = (uA >> (q * 8)) & 0xffu;
            const unsigned mB = (uB >> (q * 8)) & 0xffu;
            short8 afA, afB;
            #pragma unroll
            for (int e = 0; e < 8; ++e) {
                const float Ev = (e < 4) ? ea[e] : eb[e - 4];
                const float Fv = (e < 4) ? fa[e] : fb2[e - 4];
                const float pa = fmaxf(e1a * Ev, f1a * Fv);
                const float pb = fmaxf(e1b * Ev, f1b * Fv);
                afA[e] = bf16b(((mA >> e) & 1u) ? pa : 0.f);
                afB[e] = bf16b(((mB >> e) & 1u) ? pb : 0.f);
            }
            #pragma unroll
            for (int dblk = 0; dblk < 4; ++dblk) {
                const short8 bfrag = *(const short8*)(base + h * 4096 + dblk * 1024 + lane * 16);
                acc[dblk][0] = __builtin_amdgcn_mfma_f32_16x16x32_bf16(afA, bfrag, acc[dblk][0], 0, 0, 0);
                acc[dblk][1] = __builtin_amdgcn_mfma_f32_16x16x32_bf16(afB, bfrag, acc[dblk][1], 0, 0, 0);
            }
            accD[0] = __builtin_amdgcn_mfma_f32_16x16x32_bf16(afA, ones, accD[0], 0, 0, 0);
            accD[1] = __builtin_amdgcn_mfma_f32_16x16x32_bf16(afB, ones, accD[1], 0, 0, 0);
        }
    }
    // ---- epilogue: jseg-pair reduction in LDS, write partials for half 'by' ----
    __syncthreads();
    float* ep = (float*)stage;           // 4 waves x 2560 f32 = 40 KB
    if (jseg == 1) {
        float* dst = ep + (w - 4) * 2560;
        #pragma unroll
        for (int dblk = 0; dblk < 4; ++dblk)
            #pragma unroll
            for (int sub = 0; sub < 2; ++sub)
                #pragma unroll
                for (int r = 0; r < 4; ++r)
                    dst[(dblk * 8 + sub * 4 + r) * 64 + lane] = acc[dblk][sub][r];
        #pragma unroll
        for (int sub = 0; sub < 2; ++sub)
            #pragma unroll
            for (int r = 0; r < 4; ++r)
                dst[(32 + sub * 4 + r) * 64 + lane] = accD[sub][r];
    }
    __syncthreads();
    if (jseg == 0) {
        const float* src = ep + w * 2560;
        float* po = (by == 0) ? pA : pB;
        #pragma unroll
        for (int sub = 0; sub < 2; ++sub) {
            #pragma unroll
            for (int r = 0; r < 4; ++r) {
                const int row = i0 + sub * 16 + q * 4 + r;   // C/D: row=(lane>>4)*4+reg
                #pragma unroll
                for (int dblk = 0; dblk < 4; ++dblk) {
                    const float v = acc[dblk][sub][r] + src[(dblk * 8 + sub * 4 + r) * 64 + lane];
                    po[(size_t)row * OUT_COLS + head * DHEAD + dblk * 16 + il] = v;
                }
                if (il == 0) {
                    const float d = accD[sub][r] + src[(32 + sub * 4 + r) * 64 + lane];
                    pDen[by * (NHEADS * N_NODES) + head * N_NODES + row] = d;
                }
            }
        }
    }
}

// ---- Kernel F: combine 2 j-half partials, divide, bias ----
__global__ __launch_bounds__(256) void k_fin(
    const float* __restrict__ pB, const float* __restrict__ pDen,
    const float* __restrict__ bias, float* __restrict__ outp)
{
    const int gid = (int)blockIdx.x * 256 + (int)threadIdx.x;  // 262144
    const int i = gid >> 6;
    const int c4 = (gid & 63) << 2;
    const int head = c4 >> 6;
    const float4 v0 = *(const float4*)(outp + (size_t)i * OUT_COLS + c4);
    const float4 v1 = *(const float4*)(pB + (size_t)i * OUT_COLS + c4);
    const float d = pDen[head * N_NODES + i] + pDen[NHEADS * N_NODES + head * N_NODES + i];
    const float inv = 1.0f / d;
    const float4 bb = *(const float4*)(bias + c4);
    float4 r;
    r.x = (v0.x + v1.x) * inv + bb.x;
    r.y = (v0.y + v1.y) * inv + bb.y;
    r.z = (v0.z + v1.z) * inv + bb.z;
    r.w = (v0.w + v1.w) * inv + bb.w;
    *(float4*)(outp + (size_t)i * OUT_COLS + c4) = r;
}

extern "C" void kernel_launch(void* const* d_in, const int* in_sizes, int n_in,
                              void* d_out, int out_size, void* d_ws, size_t ws_size,
                              hipStream_t stream) {
    const float* features  = (const float*)d_in[0];
    const int*   adjacency = (const int*)d_in[1];
    const float* weights   = (const float*)d_in[2];
    const float* attention = (const float*)d_in[3];
    const float* bias      = (const float*)d_in[4];
    float* out = (float*)d_out;

    char* ws = (char*)d_ws;
    char*     hP     = ws;                                          // 2 MB
    float*    E1     = (float*)(ws + 2u*1024*1024);                 // 64 KB
    float*    F1     = (float*)(ws + 2u*1024*1024 +  64u*1024);
    float*    E2p    = (float*)(ws + 2u*1024*1024 + 128u*1024);
    float*    F2p    = (float*)(ws + 2u*1024*1024 + 192u*1024);
    unsigned* bits32 = (unsigned*)(ws + 2u*1024*1024 + 256u*1024);  // 2 MB
    float*    pB     = (float*)(ws + 4u*1024*1024 + 256u*1024);     // 4 MB
    float*    pDen   = (float*)(ws + 8u*1024*1024 + 256u*1024);     // 128 KB

    k_prep2<<<dim3(1536), 256, 0, stream>>>(features, weights, attention, adjacency,
                                            hP, E1, F1, E2p, F2p, bits32);
    k_gat<<<dim3(128, 2), 512, 0, stream>>>(bits32, hP, E1, F1, E2p, F2p,
                                            out /*pA*/, pB, pDen);
    k_fin<<<dim3(1024), 256, 0, stream>>>(pB, pDen, bias, out);
}